// Round 9
// baseline (152.256 us; speedup 1.0000x reference)
//
#include <hip/hip_runtime.h>

// LocalAttention, MFMA bf16, round 16 = T3/T4 strip pipeline with all-DMA staging.
// B=4, L=2048, H=16, E=D=64, window=64. fp32 in/out; bf16 MFMA; fp32 accumulate.
//
// r15 post-mortem: all-DMA staging (zero register-destined loads) still 2.9 TB/s
// -> compiler serialization exonerated. Remaining structural hole: loads are in
// flight only between issue and the NEAREST barrier; the compute phase always
// runs with an empty memory pipe. This round closes it with the guide's T3+T4:
//
//   Persistent strip of ST=8 q-tiles. Double-buffered K/V staged ONLY via
//   global_load_lds. Per iteration:
//     issue DMA[t+1] -> buf[(t+1)&1]   (64 KB, no reg dest, cannot serialize)
//     compute tile t from buf[t&1]     (DMA flies under ALL of it)
//     __syncthreads()                  (vmcnt(0) drain lands AFTER compute --
//                                       exactly the T4 counted-wait effect)
//     store O(t)                       (after barrier: retires under next QK)
//
//   - LDS 2 x (K 32KB + V 32KB) = 131072 B -> 1 block/CU; grid = 256 = #CUs,
//     zero tail. Occupancy ~12% is EXPECTED; memory duty is the metric.
//   - Q prefetched to registers (4 loads/tile, counted-wait, trivial).
//   - Per-tile compute identical to r15 (verified): swapped QK from
//     chunk-swizzled K, in-register P, linear-V scalar gather, index masks.
//
// TELL: hbm_gbps >= 4 => duty was the limiter (expect ~22-30 us/dispatch).
//       hbm_gbps <= 3.1 with 64 KB in flight under compute => pattern ceiling
//       confirmed; declare ROOFLINE next round.

#define B_ 4
#define L_ 2048
#define H_ 16
#define E_ 64
#define D_ 64
#define ST 8

typedef __attribute__((ext_vector_type(8))) short short8;
typedef __attribute__((ext_vector_type(4))) float f32x4;

__device__ __forceinline__ unsigned int f2bf(float x) {
  unsigned int b = __float_as_uint(x);
  b += 0x7fffu + ((b >> 16) & 1u);   // RNE to bf16
  return b >> 16;
}
__device__ __forceinline__ unsigned int pack2(float a, float b) {
  return f2bf(a) | (f2bf(b) << 16);
}
__device__ __forceinline__ short8 pack8(const f32x4& a, const f32x4& b) {
  union { short8 s; uint4 u; } r;
  r.u = make_uint4(pack2(a[0], a[1]), pack2(a[2], a[3]),
                   pack2(b[0], b[1]), pack2(b[2], b[3]));
  return r.s;
}
__device__ __forceinline__ int clampL(int k) {
  return k < 0 ? 0 : (k > (L_ - 1) ? (L_ - 1) : k);
}

// Stage one tile's K (chunk-swizzled) + V (linear) via global_load_lds.
__device__ __forceinline__ void stage_tile(const float* __restrict__ kg,
                                           const float* __restrict__ vg,
                                           int b, int h, int q0t,
                                           int t, int wave,
                                           float* Kb, float* Vb) {
  const int kst = q0t - 32;
  #pragma unroll
  for (int it = 0; it < 8; ++it) {
    const int cid = t + it * 256;
    const int row = cid >> 4, ch = cid & 15;
    const int chs = ch ^ (row & 15);
    const int key = clampL(kst + row);
    const float* src = kg + ((size_t)(b * L_ + key) * H_ + h) * E_ + chs * 4;
    float* dst = Kb + (it * 256 + wave * 64) * 4;
    __builtin_amdgcn_global_load_lds(
        (__attribute__((address_space(1))) void*)src,
        (__attribute__((address_space(3))) void*)dst, 16, 0, 0);
  }
  #pragma unroll
  for (int it = 0; it < 8; ++it) {
    const int cid = t + it * 256;
    const int row = cid >> 4, ch = cid & 15;
    const int key = clampL(kst + row);
    const float* src = vg + ((size_t)(b * L_ + key) * H_ + h) * D_ + ch * 4;
    float* dst = Vb + (it * 256 + wave * 64) * 4;
    __builtin_amdgcn_global_load_lds(
        (__attribute__((address_space(1))) void*)src,
        (__attribute__((address_space(3))) void*)dst, 16, 0, 0);
  }
}

__global__ __launch_bounds__(256, 1)
void local_attn_mfma(const float* __restrict__ qg,
                     const float* __restrict__ kg,
                     const float* __restrict__ vg,
                     float* __restrict__ og) {
  __shared__ __align__(16) float Ks32[2][128 * 64];  // 2 x 32 KB, chunk-swizzled
  __shared__ __align__(16) float Vs32[2][128 * 64];  // 2 x 32 KB, linear [key][dim]

  const int t = threadIdx.x;
  const int tile0 = blockIdx.x * ST;
  const int h = blockIdx.y;
  const int b = blockIdx.z;
  const int wave = t >> 6;
  const int lane = t & 63;
  const int col16 = lane & 15;
  const int quad = lane >> 4;

  // Swizzled chunk slots for K fragment reads (row&15 == col16 always).
  const int s0 = (2 * quad) ^ col16;
  const int s1 = (2 * quad + 1) ^ col16;
  const int s2 = (2 * quad + 8) ^ col16;
  const int s3 = (2 * quad + 9) ^ col16;

  // ---- Prologue: Q[0] regs + DMA tile 0 -> buf 0 ----
  f32x4 qp0, qp1, qp2, qp3;
  {
    const float* pq = qg + ((size_t)(b * L_ + tile0 * 64 + wave * 16 + col16) * H_ + h) * E_ + quad * 8;
    qp0 = *(const f32x4*)pq;
    qp1 = *(const f32x4*)(pq + 4);
    qp2 = *(const f32x4*)(pq + 32);
    qp3 = *(const f32x4*)(pq + 36);
  }
  stage_tile(kg, vg, b, h, tile0 * 64, t, wave, &Ks32[0][0], &Vs32[0][0]);
  short8 qa0 = pack8(qp0, qp1);
  short8 qa1 = pack8(qp2, qp3);
  __syncthreads();

  #pragma unroll 2
  for (int s = 0; s < ST; ++s) {
    float* Kb = &Ks32[s & 1][0];
    float* Vb = &Vs32[s & 1][0];
    const int q0 = (tile0 + s) * 64;
    const int kstart = q0 - 32;

    // ---- Issue next tile's Q regs + 64 KB DMA; they fly under ALL of tile s ----
    if (s + 1 < ST) {
      const float* pq = qg + ((size_t)(b * L_ + (q0 + 64) + wave * 16 + col16) * H_ + h) * E_ + quad * 8;
      qp0 = *(const f32x4*)pq;
      qp1 = *(const f32x4*)(pq + 4);
      qp2 = *(const f32x4*)(pq + 32);
      qp3 = *(const f32x4*)(pq + 36);
      stage_tile(kg, vg, b, h, q0 + 64, t, wave,
                 &Ks32[(s + 1) & 1][0], &Vs32[(s + 1) & 1][0]);
    }

    // ---- QK swapped: acc = S^T. Lane: S[key=wave*16+tt*16+quad*4+r][q=col16] ----
    f32x4 acc[5];
    #pragma unroll
    for (int tt = 0; tt < 5; ++tt) {
      const int krow = wave * 16 + tt * 16 + col16;
      const float* Kr = Kb + krow * 64;
      const short8 kb0 = pack8(*(const f32x4*)(Kr + s0 * 4), *(const f32x4*)(Kr + s1 * 4));
      const short8 kb1 = pack8(*(const f32x4*)(Kr + s2 * 4), *(const f32x4*)(Kr + s3 * 4));
      f32x4 c = {0.f, 0.f, 0.f, 0.f};
      c = __builtin_amdgcn_mfma_f32_16x16x32_bf16(kb0, qa0, c, 0, 0, 0);
      c = __builtin_amdgcn_mfma_f32_16x16x32_bf16(kb1, qa1, c, 0, 0, 0);
      acc[tt] = c;
    }

    // ---- Mask + softmax (query=col16; keys over tt,quad,r; reduce 16,32) ----
    float mx = -1e30f;
    #pragma unroll
    for (int tt = 0; tt < 5; ++tt)
      #pragma unroll
      for (int r = 0; r < 4; ++r) {
        const int k_loc = tt * 16 + quad * 4 + r;          // key rel to wave band
        const int gkey = kstart + wave * 16 + k_loc;       // global key
        const bool ok = ((unsigned)(k_loc - col16) < 64u) &&
                        ((unsigned)gkey < (unsigned)L_);
        const float v = ok ? acc[tt][r] * 0.125f : -1e30f; // scale = 1/sqrt(64)
        acc[tt][r] = v;
        mx = fmaxf(mx, v);
      }
    mx = fmaxf(mx, __shfl_xor(mx, 16));
    mx = fmaxf(mx, __shfl_xor(mx, 32));
    float sum = 0.f;
    #pragma unroll
    for (int tt = 0; tt < 5; ++tt)
      #pragma unroll
      for (int r = 0; r < 4; ++r) {
        const float e = __expf(acc[tt][r] - mx);
        acc[tt][r] = e;
        sum += e;
      }
    sum += __shfl_xor(sum, 16);
    sum += __shfl_xor(sum, 32);
    const float inv = 1.0f / sum;        // >= 32 valid keys -> sum >= 1

    // ---- P -> PV A-frags in register: pa[ks] elem j = acc[2ks+(j>>2)][j&3] ----
    short8 pa[3];
    {
      union { short8 s8; uint4 u4; } w;
      w.u4 = make_uint4(pack2(acc[0][0] * inv, acc[0][1] * inv),
                        pack2(acc[0][2] * inv, acc[0][3] * inv),
                        pack2(acc[1][0] * inv, acc[1][1] * inv),
                        pack2(acc[1][2] * inv, acc[1][3] * inv));
      pa[0] = w.s8;
      w.u4 = make_uint4(pack2(acc[2][0] * inv, acc[2][1] * inv),
                        pack2(acc[2][2] * inv, acc[2][3] * inv),
                        pack2(acc[3][0] * inv, acc[3][1] * inv),
                        pack2(acc[3][2] * inv, acc[3][3] * inv));
      pa[1] = w.s8;
      w.u4 = make_uint4(pack2(acc[4][0] * inv, acc[4][1] * inv),
                        pack2(acc[4][2] * inv, acc[4][3] * inv), 0u, 0u);
      pa[2] = w.s8;
    }

    // ---- PV: B elem j = V[slot][dim], slot = wave*16+32ks+16(j>>2)+4quad+(j&3),
    //      dim = nt*16+col16. Overhang (ks==2, j>=4) -> slot&127 (P==0 there). ----
    f32x4 oacc[4];
    #pragma unroll
    for (int nt = 0; nt < 4; ++nt) oacc[nt] = (f32x4){0.f, 0.f, 0.f, 0.f};
    #pragma unroll
    for (int nt = 0; nt < 4; ++nt) {
      const int dim = nt * 16 + col16;
      #pragma unroll
      for (int ks = 0; ks < 3; ++ks) {
        f32x4 va, vb4;
        #pragma unroll
        for (int j = 0; j < 8; ++j) {
          int slot = wave * 16 + ks * 32 + ((j >> 2) << 4) + quad * 4 + (j & 3);
          if (ks == 2 && j >= 4) slot &= 127;   // compile-time-resolved guard
          const float vv = Vb[slot * 64 + dim];
          if (j < 4) va[j] = vv; else vb4[j - 4] = vv;
        }
        oacc[nt] = __builtin_amdgcn_mfma_f32_16x16x32_bf16(pa[ks], pack8(va, vb4), oacc[nt], 0, 0, 0);
      }
    }

    // ---- Pack next tile's Q (counted wait; DMA stays in flight) ----
    short8 qn0, qn1;
    if (s + 1 < ST) { qn0 = pack8(qp0, qp1); qn1 = pack8(qp2, qp3); }

    __syncthreads();   // vmcnt(0) drain lands AFTER the full compute phase

    // ---- Store O(s) after the barrier: retires under next tile's QK ----
    #pragma unroll
    for (int r = 0; r < 4; ++r) {
      const int q = q0 + wave * 16 + quad * 4 + r;
      float* orow = og + ((size_t)(b * L_ + q) * H_ + h) * D_;
      #pragma unroll
      for (int nt = 0; nt < 4; ++nt)
        orow[nt * 16 + col16] = oacc[nt][r];
    }

    if (s + 1 < ST) { qa0 = qn0; qa1 = qn1; }
  }
}

extern "C" void kernel_launch(void* const* d_in, const int* in_sizes, int n_in,
                              void* d_out, int out_size, void* d_ws, size_t ws_size,
                              hipStream_t stream) {
  const float* q = (const float*)d_in[0];
  const float* k = (const float*)d_in[1];
  const float* v = (const float*)d_in[2];
  float* o = (float*)d_out;
  dim3 grid(L_ / (64 * ST), H_, B_);
  local_attn_mfma<<<grid, dim3(256), 0, stream>>>(q, k, v, o);
}

// Round 10
// 138.344 us; speedup vs baseline: 1.1006x; 1.1006x over previous
//
#include <hip/hip_runtime.h>

// LocalAttention, MFMA bf16, round 17 = r12 (best, 40.4us) + T1 XCD-aware swizzle.
// B=4, L=2048, H=16, E=D=64, window=64. fp32 in/out; bf16 MFMA; fp32 accumulate.
//
// r16 post-mortem: depth-1 DMA pipeline at 1 block/CU inverted the bottleneck
// (prefetch done in 2.7us, compute 6.7us latency-bound -> BW 1.6 TB/s). Best
// remains r12/r15 at ~40.4us = 45% of fill-kernel HBM duty; Little's law says
// phase-structured blocks average ~half the 22 KB/CU outstanding needed.
//
// This round: ONE variable on the r12 base -- XCD-aware block swizzle (T1,
// +10-12% A/B-verified on HBM-bound GEMM, m192). Consecutive q-tiles of the
// same (b,h) share 50% of K/V rows (halo) and re-read Q/K/V across the grid;
// default round-robin scatters them over 8 incoherent L2s. Remap so each XCD
// owns 8 contiguous (q-tile x h) planes: halo re-reads become local-L2 hits
// (~200cy vs 400-900cy), raising delivered BW at the same outstanding bytes.
//   grid = 1D 2048 (= 8 x 256, bijective): logical = (bid%8)*256 + bid/8;
//   x = logical&31 (q-tile), y = (logical>>5)&15 (h), z = logical>>9 (b).
//
// Structure otherwise BYTE-IDENTICAL to r12:
//   - K staged fp32 via 8x global_load_lds (chunk-swizzled source), zero VGPRs.
//   - V reg-staged -> transposed bf16 Vt; Q reg-loaded; launch_bounds(256,3).
//   - Swapped QK (acc = S^T), in-register P -> PV A-frags, index-based mask.
//   - LDS = Ks32 32KB + Vt 19KB = 52224 B -> 3 blocks/CU. ONE barrier.
// Null tell: <3% -> structure is at its practical plateau; ROOFLINE write-up.

#define B_ 4
#define L_ 2048
#define H_ 16
#define E_ 64
#define D_ 64
#define VT_STRIDE 152

typedef __attribute__((ext_vector_type(8))) short short8;
typedef __attribute__((ext_vector_type(4))) float f32x4;

__device__ __forceinline__ unsigned int f2bf(float x) {
  unsigned int b = __float_as_uint(x);
  b += 0x7fffu + ((b >> 16) & 1u);   // RNE to bf16
  return b >> 16;
}
__device__ __forceinline__ unsigned int pack2(float a, float b) {
  return f2bf(a) | (f2bf(b) << 16);
}
__device__ __forceinline__ short8 pack8(const f32x4& a, const f32x4& b) {
  union { short8 s; uint4 u; } r;
  r.u = make_uint4(pack2(a[0], a[1]), pack2(a[2], a[3]),
                   pack2(b[0], b[1]), pack2(b[2], b[3]));
  return r.s;
}
__device__ __forceinline__ int clampL(int k) {
  return k < 0 ? 0 : (k > (L_ - 1) ? (L_ - 1) : k);
}

__global__ __launch_bounds__(256, 3)
void local_attn_mfma(const float* __restrict__ qg,
                     const float* __restrict__ kg,
                     const float* __restrict__ vg,
                     float* __restrict__ og) {
  __shared__ __align__(16) float Ks32[128 * 64];               // 32768 B, gload_lds dest
  __shared__ __align__(16) unsigned short Vt[64 * VT_STRIDE];  // 19456 B, [dim][key_rel]

  // ---- T1 XCD swizzle: HW round-robins bid%8 across XCDs; remap so each XCD
  //      gets a CONTIGUOUS run of 256 logical tiles (8 h-planes of one b). ----
  const int bid = blockIdx.x;                    // 0..2047
  const int logical = (bid & 7) * 256 + (bid >> 3);
  const int q0 = (logical & 31) * 64;            // q-tile
  const int h = (logical >> 5) & 15;             // head
  const int b = logical >> 9;                    // batch

  const int t = threadIdx.x;
  const int kstart = q0 - 32;
  const int wave = t >> 6;
  const int lane = t & 63;
  const int col16 = lane & 15;
  const int quad = lane >> 4;

  // ---- V + Q register loads first (their vmcnt waits must not drain K) ----
  const int kp = t >> 2;               // key pair -> keys kstart+2kp, +2kp+1
  const int dq = t & 3;                // dim quarter: dims dq*16 .. +15
  f32x4 va[4], vc[4];
  {
    const int k0 = clampL(kstart + 2 * kp);
    const int k1 = clampL(kstart + 2 * kp + 1);
    const float* p0 = vg + ((size_t)(b * L_ + k0) * H_ + h) * D_ + dq * 16;
    const float* p1 = vg + ((size_t)(b * L_ + k1) * H_ + h) * D_ + dq * 16;
    #pragma unroll
    for (int i = 0; i < 4; ++i) va[i] = *(const f32x4*)(p0 + i * 4);
    #pragma unroll
    for (int i = 0; i < 4; ++i) vc[i] = *(const f32x4*)(p1 + i * 4);
  }
  f32x4 qf0, qf1, qf2, qf3;
  {
    const float* pq = qg + ((size_t)(b * L_ + q0 + wave * 16 + col16) * H_ + h) * E_ + quad * 8;
    qf0 = *(const f32x4*)pq;
    qf1 = *(const f32x4*)(pq + 4);
    qf2 = *(const f32x4*)(pq + 32);
    qf3 = *(const f32x4*)(pq + 36);
  }

  // ---- K staging: 8x global_load_lds, zero VGPRs, source chunk-swizzled.
  //      cid = row*16 + ch (16B chunks); LDS slot cid holds global chunk
  //      ch ^ (row & 15) of K row (clamped key kstart+row). ----
  #pragma unroll
  for (int it = 0; it < 8; ++it) {
    const int cid = t + it * 256;
    const int row = cid >> 4, ch = cid & 15;
    const int chs = ch ^ (row & 15);
    const int key = clampL(kstart + row);
    const float* src = kg + ((size_t)(b * L_ + key) * H_ + h) * E_ + chs * 4;
    float* dst = &Ks32[(it * 256 + wave * 64) * 4];   // wave-uniform base; HW adds lane*16
    __builtin_amdgcn_global_load_lds(
        (__attribute__((address_space(1))) void*)src,
        (__attribute__((address_space(3))) void*)dst, 16, 0, 0);
  }

  // ---- V pack -> Vt (bf16 transposed), zero-pad key cols 128..143 ----
  #pragma unroll
  for (int i = 0; i < 4; ++i)
    #pragma unroll
    for (int j = 0; j < 4; ++j) {
      int d = dq * 16 + i * 4 + j;
      *(unsigned int*)&Vt[d * VT_STRIDE + 2 * kp] = pack2(va[i][j], vc[i][j]);
    }
  *(uint2*)&Vt[(t >> 2) * VT_STRIDE + 128 + (t & 3) * 4] = make_uint2(0u, 0u);

  const short8 qa0 = pack8(qf0, qf1);
  const short8 qa1 = pack8(qf2, qf3);

  __syncthreads();   // the ONLY barrier; drains gload_lds + ds_writes

  // ---- QK swapped: acc = S^T tile. A = K-frag from Ks32 (swizzled chunks).
  //      Lane holds S[key = wave*16 + tt*16 + quad*4 + r][query = col16].
  //      krow & 15 == col16, so the read-side XOR is just ^col16. ----
  const int c0 = (2 * quad) ^ col16;        // chunk of dims quad*8..+3
  const int c1 = (2 * quad + 1) ^ col16;    // dims quad*8+4..+7
  const int c2 = (2 * quad + 8) ^ col16;    // dims 32+quad*8..+3
  const int c3 = (2 * quad + 9) ^ col16;    // dims 32+quad*8+4..+7
  f32x4 acc[5];
  #pragma unroll
  for (int tt = 0; tt < 5; ++tt) {
    const int krow = wave * 16 + tt * 16 + col16;
    const float* Kr = &Ks32[krow * 64];
    f32x4 k0 = *(const f32x4*)(Kr + c0 * 4);
    f32x4 k1 = *(const f32x4*)(Kr + c1 * 4);
    f32x4 k2 = *(const f32x4*)(Kr + c2 * 4);
    f32x4 k3 = *(const f32x4*)(Kr + c3 * 4);
    short8 kb0 = pack8(k0, k1);
    short8 kb1 = pack8(k2, k3);
    f32x4 c = {0.f, 0.f, 0.f, 0.f};
    c = __builtin_amdgcn_mfma_f32_16x16x32_bf16(kb0, qa0, c, 0, 0, 0);
    c = __builtin_amdgcn_mfma_f32_16x16x32_bf16(kb1, qa1, c, 0, 0, 0);
    acc[tt] = c;
  }

  // ---- Mask + softmax. Query = col16 (fixed per lane); keys over (tt,quad,r).
  //      Cross-lane reduce = quads only: shfl_xor 16, 32. ----
  float mx = -1e30f;
  #pragma unroll
  for (int tt = 0; tt < 5; ++tt)
    #pragma unroll
    for (int r = 0; r < 4; ++r) {
      const int k_loc = tt * 16 + quad * 4 + r;          // key rel to wave band
      const int gkey = kstart + wave * 16 + k_loc;       // global key
      const bool ok = ((unsigned)(k_loc - col16) < 64u) &&
                      ((unsigned)gkey < (unsigned)L_);
      const float v = ok ? acc[tt][r] * 0.125f : -1e30f; // scale = 1/sqrt(64)
      acc[tt][r] = v;
      mx = fmaxf(mx, v);
    }
  mx = fmaxf(mx, __shfl_xor(mx, 16));
  mx = fmaxf(mx, __shfl_xor(mx, 32));
  float s = 0.f;
  #pragma unroll
  for (int tt = 0; tt < 5; ++tt)
    #pragma unroll
    for (int r = 0; r < 4; ++r) {
      const float e = __expf(acc[tt][r] - mx);
      acc[tt][r] = e;
      s += e;
    }
  s += __shfl_xor(s, 16);
  s += __shfl_xor(s, 32);
  const float inv = 1.0f / s;          // >= 32 valid keys -> s >= 1

  // ---- P -> PV A-frags IN REGISTER (lane-local by construction).
  //      elem j of pa[ks] = P[col16][32ks+16(j>>2)+4quad+(j&3)]
  //      = acc[2ks + (j>>2)][j&3]. Tail frag: elems 4..7 = 0. ----
  short8 pa[3];
  {
    union { short8 s8; uint4 u4; } w;
    w.u4 = make_uint4(pack2(acc[0][0] * inv, acc[0][1] * inv),
                      pack2(acc[0][2] * inv, acc[0][3] * inv),
                      pack2(acc[1][0] * inv, acc[1][1] * inv),
                      pack2(acc[1][2] * inv, acc[1][3] * inv));
    pa[0] = w.s8;
    w.u4 = make_uint4(pack2(acc[2][0] * inv, acc[2][1] * inv),
                      pack2(acc[2][2] * inv, acc[2][3] * inv),
                      pack2(acc[3][0] * inv, acc[3][1] * inv),
                      pack2(acc[3][2] * inv, acc[3][3] * inv));
    pa[1] = w.s8;
    w.u4 = make_uint4(pack2(acc[4][0] * inv, acc[4][1] * inv),
                      pack2(acc[4][2] * inv, acc[4][3] * inv), 0u, 0u);
    pa[2] = w.s8;
  }

  // ---- PV: per dim-tile nt, 3 K=32 steps. B elem j = V[key(quad*8+j)][dim]:
  //      two uint2 (4 consecutive keys each) at cols base+quad*4 and +16. ----
  f32x4 oacc[4];
  #pragma unroll
  for (int nt = 0; nt < 4; ++nt) oacc[nt] = (f32x4){0.f, 0.f, 0.f, 0.f};
  #pragma unroll
  for (int nt = 0; nt < 4; ++nt) {
    const int rowb = (nt * 16 + col16) * VT_STRIDE;
    #pragma unroll
    for (int ks = 0; ks < 3; ++ks) {
      union { short8 s8; uint2 u2[2]; } vb;
      vb.u2[0] = *(const uint2*)&Vt[rowb + wave * 16 + ks * 32 + quad * 4];
      vb.u2[1] = *(const uint2*)&Vt[rowb + wave * 16 + ks * 32 + 16 + quad * 4];
      oacc[nt] = __builtin_amdgcn_mfma_f32_16x16x32_bf16(pa[ks], vb.s8, oacc[nt], 0, 0, 0);
    }
  }

  // ---- Store O (fp32). C: row = quad*4+r (query), col = col16 (dim) ----
  #pragma unroll
  for (int r = 0; r < 4; ++r) {
    const int q = q0 + wave * 16 + quad * 4 + r;
    float* orow = og + ((size_t)(b * L_ + q) * H_ + h) * D_;
    #pragma unroll
    for (int nt = 0; nt < 4; ++nt)
      orow[nt * 16 + col16] = oacc[nt][r];
  }
}

extern "C" void kernel_launch(void* const* d_in, const int* in_sizes, int n_in,
                              void* d_out, int out_size, void* d_ws, size_t ws_size,
                              hipStream_t stream) {
  const float* q = (const float*)d_in[0];
  const float* k = (const float*)d_in[1];
  const float* v = (const float*)d_in[2];
  float* o = (float*)d_out;
  dim3 grid((L_ / 64) * H_ * B_);   // 2048, 1D for bijective XCD swizzle
  local_attn_mfma<<<grid, dim3(256), 0, stream>>>(q, k, v, o);
}